// Round 1
// baseline (699.794 us; speedup 1.0000x reference)
//
#include <hip/hip_runtime.h>
#include <math.h>

// Problem constants
#define NB 1024
#define NC 5994
#define NK 512
#define NA 3
#define SCALE_F 30.0f

// Margin constants (double-precision evaluated, truncated to float)
#define COS_M_F 0.9800665778412416f
#define SIN_M_F 0.19866933079506122f
#define TH_F (-0.9800665778412416f)
#define MM_F 0.039733866159012244f
#define SUB_COS_M_F 0.9982005399352042f
#define SUB_SIN_M_F (-0.05996400647944459f)
#define SUB_TH_F (-0.9982005399352042f)
#define SUB_MM_F 0.0035978403887666754f

__device__ __forceinline__ float waveReduceSum(float v) {
#pragma unroll
  for (int off = 32; off > 0; off >>= 1) v += __shfl_down(v, off);
  return v;
}

__device__ __forceinline__ void waveArgMax(float& v, int& i) {
#pragma unroll
  for (int off = 32; off > 0; off >>= 1) {
    float ov = __shfl_down(v, off);
    int oi = __shfl_down(i, off);
    // larger value wins; tie -> smaller index ((unsigned)-1 is huge, loses)
    if (ov > v || (ov == v && (unsigned)oi < (unsigned)i)) { v = ov; i = oi; }
  }
}

// Reciprocal L2 norm per row: rn[row] = 1/max(||src[row,:]||, 1e-12)
__global__ __launch_bounds__(256) void rnorm_kernel(const float* __restrict__ src,
                                                    float* __restrict__ rn, int K) {
  const int row = blockIdx.x, tid = threadIdx.x;
  const float* p = src + (size_t)row * K;
  float ss = 0.f;
  for (int i = tid; i < K; i += 256) { float t = p[i]; ss += t * t; }
  ss = waveReduceSum(ss);
  __shared__ float sred[4];
  if ((tid & 63) == 0) sred[tid >> 6] = ss;
  __syncthreads();
  if (tid == 0) {
    float s = sred[0] + sred[1] + sred[2] + sred[3];
    rn[row] = 1.0f / fmaxf(sqrtf(s), 1e-12f);
  }
}

// cosine[b,c] = max_a dot(x[b,:], w[a,c,:]) * rxn[b] * rwn[a,c]
// 64x64 output tile per block, 256 threads (16x16), 4x4 micro-tile, BK=32.
__global__ __launch_bounds__(256) void cos_gemm(const float* __restrict__ X,
                                                const float* __restrict__ W,
                                                const float* __restrict__ rxn,
                                                const float* __restrict__ rwn,
                                                float* __restrict__ cosine) {
  __shared__ float sx[64][36];  // pad to 36 -> 144B row stride (16B aligned, conflict-friendly)
  __shared__ float sw[64][36];
  const int tid = threadIdx.x;
  const int tx = tid & 15, ty = tid >> 4;
  const int b0 = blockIdx.y * 64;
  const int c0 = blockIdx.x * 64;

  float best[4][4];
#pragma unroll
  for (int i = 0; i < 4; ++i)
#pragma unroll
    for (int j = 0; j < 4; ++j) best[i][j] = -INFINITY;

  for (int a = 0; a < NA; ++a) {
    float acc[4][4];
#pragma unroll
    for (int i = 0; i < 4; ++i)
#pragma unroll
      for (int j = 0; j < 4; ++j) acc[i][j] = 0.f;

    for (int k0 = 0; k0 < NK; k0 += 32) {
      // stage: 64x32 tiles = 512 float4 slots, 2 per thread
#pragma unroll
      for (int r = 0; r < 2; ++r) {
        const int f = tid + r * 256;
        const int row = f >> 3;
        const int c4 = (f & 7) << 2;
        const float4 xv = *(const float4*)(X + (size_t)(b0 + row) * NK + k0 + c4);
        *(float4*)&sx[row][c4] = xv;
        int cc = c0 + row;
        if (cc > NC - 1) cc = NC - 1;  // clamp (results discarded at store)
        const float4 wv = *(const float4*)(W + ((size_t)a * NC + cc) * NK + k0 + c4);
        *(float4*)&sw[row][c4] = wv;
      }
      __syncthreads();
#pragma unroll
      for (int k = 0; k < 32; k += 4) {
        float4 av[4], bv[4];
#pragma unroll
        for (int i = 0; i < 4; ++i) av[i] = *(const float4*)&sx[ty * 4 + i][k];
#pragma unroll
        for (int j = 0; j < 4; ++j) bv[j] = *(const float4*)&sw[tx * 4 + j][k];
#pragma unroll
        for (int i = 0; i < 4; ++i)
#pragma unroll
          for (int j = 0; j < 4; ++j) {
            acc[i][j] = fmaf(av[i].x, bv[j].x, acc[i][j]);
            acc[i][j] = fmaf(av[i].y, bv[j].y, acc[i][j]);
            acc[i][j] = fmaf(av[i].z, bv[j].z, acc[i][j]);
            acc[i][j] = fmaf(av[i].w, bv[j].w, acc[i][j]);
          }
      }
      __syncthreads();
    }
    // fold center a into running max (rwn > 0, monotone)
    float rw[4];
#pragma unroll
    for (int j = 0; j < 4; ++j) {
      int c = c0 + tx * 4 + j;
      if (c > NC - 1) c = NC - 1;
      rw[j] = rwn[a * NC + c];
    }
#pragma unroll
    for (int i = 0; i < 4; ++i)
#pragma unroll
      for (int j = 0; j < 4; ++j) best[i][j] = fmaxf(best[i][j], acc[i][j] * rw[j]);
  }

  float rx[4];
#pragma unroll
  for (int i = 0; i < 4; ++i) rx[i] = rxn[b0 + ty * 4 + i];
#pragma unroll
  for (int i = 0; i < 4; ++i)
#pragma unroll
    for (int j = 0; j < 4; ++j) {
      const int c = c0 + tx * 4 + j;
      if (c < NC) cosine[(size_t)(b0 + ty * 4 + i) * NC + c] = best[i][j] * rx[i];
    }
}

// Per-row: argmax (prec1), top-6 extraction, shifted softmax-sum with margin
// corrections; emits per-row loss and correctness flag.
__global__ __launch_bounds__(256) void row_loss(const float* __restrict__ cosine,
                                                const int* __restrict__ label,
                                                float* __restrict__ loss_b,
                                                float* __restrict__ corr_b) {
  __shared__ float scos[NC];
  __shared__ float swv[4];
  __shared__ int swi[4];
  __shared__ float s_sum[4];
  __shared__ float topv[6];
  __shared__ int topi[6];
  __shared__ float s_maxv;
  __shared__ int s_maxi;

  const int b = blockIdx.x, tid = threadIdx.x;
  const float* row = cosine + (size_t)b * NC;

  // load row into LDS + local argmax
  float bv = -INFINITY;
  int bi = -1;
  for (int i = tid; i < NC; i += 256) {
    const float v = row[i];
    scos[i] = v;
    if (v > bv) { bv = v; bi = i; }  // ascending scan keeps first occurrence
  }
  waveArgMax(bv, bi);
  if ((tid & 63) == 0) { swv[tid >> 6] = bv; swi[tid >> 6] = bi; }
  __syncthreads();
  if (tid == 0) {
    float mv = swv[0]; int mi = swi[0];
    for (int w = 1; w < 4; ++w)
      if (swv[w] > mv || (swv[w] == mv && (unsigned)swi[w] < (unsigned)mi)) { mv = swv[w]; mi = swi[w]; }
    s_maxv = mv; s_maxi = mi; topv[0] = mv; topi[0] = mi;
  }
  __syncthreads();
  const float maxv = s_maxv;
  const int maxi = s_maxi;

  // shifted exp-sum over full row
  float ps = 0.f;
  for (int i = tid; i < NC; i += 256) ps += expf(SCALE_F * (scos[i] - maxv));
  ps = waveReduceSum(ps);
  if ((tid & 63) == 0) s_sum[tid >> 6] = ps;

  // extract top[1..5] by masked argmax passes
  for (int e = 1; e < 6; ++e) {
    __syncthreads();
    float lv = -INFINITY;
    int li = -1;
    for (int i = tid; i < NC; i += 256) {
      bool skip = false;
#pragma unroll 5
      for (int q = 0; q < e; ++q) skip = skip || (topi[q] == i);
      if (!skip) {
        const float v = scos[i];
        if (v > lv) { lv = v; li = i; }
      }
    }
    waveArgMax(lv, li);
    if ((tid & 63) == 0) { swv[tid >> 6] = lv; swi[tid >> 6] = li; }
    __syncthreads();
    if (tid == 0) {
      float mv = swv[0]; int mi = swi[0];
      for (int w = 1; w < 4; ++w)
        if (swv[w] > mv || (swv[w] == mv && (unsigned)swi[w] < (unsigned)mi)) { mv = swv[w]; mi = swi[w]; }
      topv[e] = mv; topi[e] = mi;
    }
  }
  __syncthreads();

  if (tid == 0) {
    const float S = s_sum[0] + s_sum[1] + s_sum[2] + s_sum[3];
    const float m = SCALE_F * maxv;
    const int lab = label[b];
    const float cosL = scos[lab];
    const float sineL = sqrtf(fminf(fmaxf(1.f - cosL * cosL, 0.f), 1.f));
    const float phiL = (cosL - TH_F > 0.f) ? (cosL * COS_M_F - sineL * SIN_M_F) : (cosL - MM_F);
    float adj = expf(SCALE_F * phiL - m) - expf(SCALE_F * cosL - m);
    // idx_fixed: top-6 with label removed if present, truncated to 5
    int cnt = 0;
    for (int e = 0; e < 6 && cnt < 5; ++e) {
      if (topi[e] == lab) continue;
      const float c = topv[e];
      const float sine = sqrtf(fminf(fmaxf(1.f - c * c, 0.f), 1.f));
      const float sp = (c - SUB_TH_F > 0.f) ? (c * SUB_COS_M_F - sine * SUB_SIN_M_F) : (c - SUB_MM_F);
      adj += expf(SCALE_F * sp - m) - expf(SCALE_F * c - m);
      ++cnt;
    }
    const float Sp = S + adj;
    loss_b[b] = (logf(Sp) + m) - SCALE_F * phiL;
    corr_b[b] = (maxi == lab) ? 1.f : 0.f;
  }
}

__global__ __launch_bounds__(256) void finalize(const float* __restrict__ loss_b,
                                                const float* __restrict__ corr_b,
                                                float* __restrict__ out) {
  const int tid = threadIdx.x;
  float ls = 0.f, cs = 0.f;
  for (int i = tid; i < NB; i += 256) { ls += loss_b[i]; cs += corr_b[i]; }
  ls = waveReduceSum(ls);
  cs = waveReduceSum(cs);
  __shared__ float sl[4], sc[4];
  if ((tid & 63) == 0) { sl[tid >> 6] = ls; sc[tid >> 6] = cs; }
  __syncthreads();
  if (tid == 0) {
    const float L = sl[0] + sl[1] + sl[2] + sl[3];
    const float Cr = sc[0] + sc[1] + sc[2] + sc[3];
    out[0] = L / (float)NB;
    out[1] = Cr / (float)NB * 100.f;
  }
}

extern "C" void kernel_launch(void* const* d_in, const int* in_sizes, int n_in,
                              void* d_out, int out_size, void* d_ws, size_t ws_size,
                              hipStream_t stream) {
  const float* x = (const float*)d_in[0];      // [1024, 512]
  const float* w = (const float*)d_in[1];      // [3, 5994, 512]
  const int* label = (const int*)d_in[2];      // [1024]
  float* out = (float*)d_out;                  // [2] = {loss, prec1}
  float* ws = (float*)d_ws;

  float* rxn = ws;                             // 1024
  float* rwn = ws + 1024;                      // 3*5994 = 17982
  float* cosine = ws + 32768;                  // 1024*5994
  float* loss_b = cosine + (size_t)NB * NC;    // 1024
  float* corr_b = loss_b + NB;                 // 1024

  rnorm_kernel<<<NB, 256, 0, stream>>>(x, rxn, NK);
  rnorm_kernel<<<NA * NC, 256, 0, stream>>>(w, rwn, NK);
  cos_gemm<<<dim3((NC + 63) / 64, NB / 64), 256, 0, stream>>>(x, w, rxn, rwn, cosine);
  row_loss<<<NB, 256, 0, stream>>>(cosine, label, loss_b, corr_b);
  finalize<<<1, 256, 0, stream>>>(loss_b, corr_b, out);
}

// Round 2
// 110.714 us; speedup vs baseline: 6.3207x; 6.3207x over previous
//
#include <hip/hip_runtime.h>
#include <math.h>

// Problem constants
#define NB 1024
#define NC 5994
#define NCP 6016   // NC padded to multiple of 128 (47*128)
#define NK 512
#define NA 3
#define SCALE_F 30.0f

// Margin constants
#define COS_M_F 0.9800665778412416f
#define SIN_M_F 0.19866933079506122f
#define TH_F (-0.9800665778412416f)
#define MM_F 0.039733866159012244f
#define SUB_COS_M_F 0.9982005399352042f
#define SUB_SIN_M_F (-0.05996400647944459f)
#define SUB_TH_F (-0.9982005399352042f)
#define SUB_MM_F 0.0035978403887666754f

typedef __attribute__((ext_vector_type(8))) short short8;   // 8 bf16 (4 VGPRs)
typedef __attribute__((ext_vector_type(4))) float f32x4;    // MFMA accumulator

__device__ __forceinline__ float waveReduceSum(float v) {
#pragma unroll
  for (int off = 32; off > 0; off >>= 1) v += __shfl_down(v, off);
  return v;
}

__device__ __forceinline__ void waveArgMax(float& v, int& i) {
#pragma unroll
  for (int off = 32; off > 0; off >>= 1) {
    float ov = __shfl_down(v, off);
    int oi = __shfl_down(i, off);
    if (ov > v || (ov == v && (unsigned)oi < (unsigned)i)) { v = ov; i = oi; }
  }
}

__device__ __forceinline__ ushort f2bf(float f) {
  // round-to-nearest-even bf16 (values here are small normals; no NaN/inf)
  unsigned u = __float_as_uint(f);
  u += 0x7FFFu + ((u >> 16) & 1u);
  return (ushort)(u >> 16);
}

__device__ __forceinline__ void load_lds16(const ushort* g, ushort* l) {
  __builtin_amdgcn_global_load_lds(
      (const __attribute__((address_space(1))) unsigned int*)g,
      (__attribute__((address_space(3))) unsigned int*)l, 16, 0, 0);
}

// Fused L2-normalize + bf16 convert. One wave per row.
// blocks [0,NB): x rows -> xb.  blocks [NB, NB+NA*NCP): w rows -> wb (pad rows zeroed).
__global__ __launch_bounds__(64) void norm_convert(const float* __restrict__ x,
                                                   const float* __restrict__ w,
                                                   ushort* __restrict__ xb,
                                                   ushort* __restrict__ wb) {
  const int blk = blockIdx.x;
  const int lane = threadIdx.x;
  const float* src;
  ushort* dst;
  if (blk < NB) {
    src = x + (size_t)blk * NK;
    dst = xb + (size_t)blk * NK;
  } else {
    const int r = blk - NB;           // 0 .. NA*NCP-1
    const int a = r / NCP, c = r % NCP;
    dst = wb + (size_t)r * NK;
    if (c >= NC) {                    // zero-fill padding row
      ushort4 z = {0, 0, 0, 0};
      *(ushort4*)(dst + lane * 4) = z;
      *(ushort4*)(dst + 256 + lane * 4) = z;
      return;
    }
    src = w + ((size_t)a * NC + c) * NK;
  }
  const float4 v0 = *(const float4*)(src + lane * 4);
  const float4 v1 = *(const float4*)(src + 256 + lane * 4);
  float ss = v0.x * v0.x + v0.y * v0.y + v0.z * v0.z + v0.w * v0.w +
             v1.x * v1.x + v1.y * v1.y + v1.z * v1.z + v1.w * v1.w;
  ss = waveReduceSum(ss);
  ss = __shfl(ss, 0);
  const float rn = 1.0f / fmaxf(sqrtf(ss), 1e-12f);
  ushort4 o0 = {f2bf(v0.x * rn), f2bf(v0.y * rn), f2bf(v0.z * rn), f2bf(v0.w * rn)};
  ushort4 o1 = {f2bf(v1.x * rn), f2bf(v1.y * rn), f2bf(v1.z * rn), f2bf(v1.w * rn)};
  *(ushort4*)(dst + lane * 4) = o0;
  *(ushort4*)(dst + 256 + lane * 4) = o1;
}

// cosine[b,c] = max_a dot(xn[b,:], wn[a,c,:])  via bf16 MFMA, fp32 accum.
// 128x128 tile, 256 threads = 4 waves (2x2), each wave owns 64x64.
// BK=32, global_load_lds(16B) into linear LDS [128][32] bf16 (m97 structure).
__global__ __launch_bounds__(256) void cos_gemm_mfma(const ushort* __restrict__ Xb,
                                                     const ushort* __restrict__ Wb,
                                                     float* __restrict__ cosine) {
  __shared__ ushort sA[128 * 32];  // 8 KB
  __shared__ ushort sB[128 * 32];  // 8 KB
  const int tid = threadIdx.x;
  const int lane = tid & 63;
  const int w = tid >> 6;
  const int wr = w >> 1, wc = w & 1;
  const int b0 = blockIdx.y * 128;
  const int c0 = blockIdx.x * 128;

  // staging geometry: wave w fills LDS slots [w*2, w*2+1], each slot = 1024 B
  // = 16 rows of the [128][32] bf16 tile. lane covers 16 B = 8 bf16.
  const int e0 = w * 2;
  const int srow = e0 * 16 + (lane >> 2);
  const int scol = (lane & 3) * 8;
  const ushort* gA0 = Xb + (size_t)(b0 + srow) * NK + scol;
  const ushort* gA1 = gA0 + (size_t)16 * NK;
  const ushort* gBb = Wb + (size_t)(c0 + srow) * NK + scol;
  ushort* lA0 = &sA[e0 * 512];
  ushort* lA1 = &sA[(e0 + 1) * 512];
  ushort* lB0 = &sB[e0 * 512];
  ushort* lB1 = &sB[(e0 + 1) * 512];

  // fragment-read geometry
  const int r = lane & 15;
  const int kg = lane >> 4;
  const int offA = (wr * 64 + r) * 32 + kg * 8;  // + mi*512
  const int offB = (wc * 64 + r) * 32 + kg * 8;  // + ni*512

  f32x4 best[4][4];
#pragma unroll
  for (int i = 0; i < 4; ++i)
#pragma unroll
    for (int j = 0; j < 4; ++j)
#pragma unroll
      for (int q = 0; q < 4; ++q) best[i][j][q] = -INFINITY;

  for (int a = 0; a < NA; ++a) {
    f32x4 acc[4][4];
#pragma unroll
    for (int i = 0; i < 4; ++i)
#pragma unroll
      for (int j = 0; j < 4; ++j) acc[i][j] = (f32x4)(0.f);

    const ushort* gB0 = gBb + (size_t)a * NCP * NK;
    const ushort* gB1 = gB0 + (size_t)16 * NK;

    for (int k0 = 0; k0 < NK; k0 += 32) {
      __syncthreads();  // all waves done reading previous tile
      load_lds16(gA0 + k0, lA0);
      load_lds16(gA1 + k0, lA1);
      load_lds16(gB0 + k0, lB0);
      load_lds16(gB1 + k0, lB1);
      __syncthreads();  // vmcnt(0) drain: tiles resident

      short8 af[4], bf[4];
#pragma unroll
      for (int mi = 0; mi < 4; ++mi) af[mi] = *(const short8*)&sA[offA + mi * 512];
#pragma unroll
      for (int ni = 0; ni < 4; ++ni) bf[ni] = *(const short8*)&sB[offB + ni * 512];
#pragma unroll
      for (int mi = 0; mi < 4; ++mi)
#pragma unroll
        for (int ni = 0; ni < 4; ++ni)
          acc[mi][ni] = __builtin_amdgcn_mfma_f32_16x16x32_bf16(af[mi], bf[ni],
                                                                acc[mi][ni], 0, 0, 0);
    }
#pragma unroll
    for (int i = 0; i < 4; ++i)
#pragma unroll
      for (int j = 0; j < 4; ++j)
#pragma unroll
        for (int q = 0; q < 4; ++q) best[i][j][q] = fmaxf(best[i][j][q], acc[i][j][q]);
  }

  // C/D layout: col = lane&15, row = (lane>>4)*4 + q   [measured m89/m91]
  const int q4 = (lane >> 4) * 4;
#pragma unroll
  for (int ni = 0; ni < 4; ++ni) {
    const int col = c0 + wc * 64 + ni * 16 + r;
    if (col < NC) {
#pragma unroll
      for (int mi = 0; mi < 4; ++mi) {
        const int row0 = b0 + wr * 64 + mi * 16 + q4;
#pragma unroll
        for (int q = 0; q < 4; ++q)
          cosine[(size_t)(row0 + q) * NC + col] = best[mi][ni][q];
      }
    }
  }
}

// Per-row: argmax (prec1), top-6 extraction, shifted softmax-sum with margin
// corrections; emits per-row loss and correctness flag.
__global__ __launch_bounds__(256) void row_loss(const float* __restrict__ cosine,
                                                const int* __restrict__ label,
                                                float* __restrict__ loss_b,
                                                float* __restrict__ corr_b) {
  __shared__ float scos[NC];
  __shared__ float swv[4];
  __shared__ int swi[4];
  __shared__ float s_sum[4];
  __shared__ float topv[6];
  __shared__ int topi[6];
  __shared__ float s_maxv;
  __shared__ int s_maxi;

  const int b = blockIdx.x, tid = threadIdx.x;
  const float* row = cosine + (size_t)b * NC;

  float bv = -INFINITY;
  int bi = -1;
  for (int i = tid; i < NC; i += 256) {
    const float v = row[i];
    scos[i] = v;
    if (v > bv) { bv = v; bi = i; }
  }
  waveArgMax(bv, bi);
  if ((tid & 63) == 0) { swv[tid >> 6] = bv; swi[tid >> 6] = bi; }
  __syncthreads();
  if (tid == 0) {
    float mv = swv[0]; int mi = swi[0];
    for (int ww = 1; ww < 4; ++ww)
      if (swv[ww] > mv || (swv[ww] == mv && (unsigned)swi[ww] < (unsigned)mi)) { mv = swv[ww]; mi = swi[ww]; }
    s_maxv = mv; s_maxi = mi; topv[0] = mv; topi[0] = mi;
  }
  __syncthreads();
  const float maxv = s_maxv;
  const int maxi = s_maxi;

  float ps = 0.f;
  for (int i = tid; i < NC; i += 256) ps += expf(SCALE_F * (scos[i] - maxv));
  ps = waveReduceSum(ps);
  if ((tid & 63) == 0) s_sum[tid >> 6] = ps;

  for (int e = 1; e < 6; ++e) {
    __syncthreads();
    float lv = -INFINITY;
    int li = -1;
    for (int i = tid; i < NC; i += 256) {
      bool skip = false;
#pragma unroll 5
      for (int q = 0; q < e; ++q) skip = skip || (topi[q] == i);
      if (!skip) {
        const float v = scos[i];
        if (v > lv) { lv = v; li = i; }
      }
    }
    waveArgMax(lv, li);
    if ((tid & 63) == 0) { swv[tid >> 6] = lv; swi[tid >> 6] = li; }
    __syncthreads();
    if (tid == 0) {
      float mv = swv[0]; int mi = swi[0];
      for (int ww = 1; ww < 4; ++ww)
        if (swv[ww] > mv || (swv[ww] == mv && (unsigned)swi[ww] < (unsigned)mi)) { mv = swv[ww]; mi = swi[ww]; }
      topv[e] = mv; topi[e] = mi;
    }
  }
  __syncthreads();

  if (tid == 0) {
    const float S = s_sum[0] + s_sum[1] + s_sum[2] + s_sum[3];
    const float m = SCALE_F * maxv;
    const int lab = label[b];
    const float cosL = scos[lab];
    const float sineL = sqrtf(fminf(fmaxf(1.f - cosL * cosL, 0.f), 1.f));
    const float phiL = (cosL - TH_F > 0.f) ? (cosL * COS_M_F - sineL * SIN_M_F) : (cosL - MM_F);
    float adj = expf(SCALE_F * phiL - m) - expf(SCALE_F * cosL - m);
    int cnt = 0;
    for (int e = 0; e < 6 && cnt < 5; ++e) {
      if (topi[e] == lab) continue;
      const float c = topv[e];
      const float sine = sqrtf(fminf(fmaxf(1.f - c * c, 0.f), 1.f));
      const float sp = (c - SUB_TH_F > 0.f) ? (c * SUB_COS_M_F - sine * SUB_SIN_M_F) : (c - SUB_MM_F);
      adj += expf(SCALE_F * sp - m) - expf(SCALE_F * c - m);
      ++cnt;
    }
    const float Sp = S + adj;
    loss_b[b] = (logf(Sp) + m) - SCALE_F * phiL;
    corr_b[b] = (maxi == lab) ? 1.f : 0.f;
  }
}

__global__ __launch_bounds__(256) void finalize(const float* __restrict__ loss_b,
                                                const float* __restrict__ corr_b,
                                                float* __restrict__ out) {
  const int tid = threadIdx.x;
  float ls = 0.f, cs = 0.f;
  for (int i = tid; i < NB; i += 256) { ls += loss_b[i]; cs += corr_b[i]; }
  ls = waveReduceSum(ls);
  cs = waveReduceSum(cs);
  __shared__ float sl[4], sc[4];
  if ((tid & 63) == 0) { sl[tid >> 6] = ls; sc[tid >> 6] = cs; }
  __syncthreads();
  if (tid == 0) {
    const float L = sl[0] + sl[1] + sl[2] + sl[3];
    const float Cr = sc[0] + sc[1] + sc[2] + sc[3];
    out[0] = L / (float)NB;
    out[1] = Cr / (float)NB * 100.f;
  }
}

extern "C" void kernel_launch(void* const* d_in, const int* in_sizes, int n_in,
                              void* d_out, int out_size, void* d_ws, size_t ws_size,
                              hipStream_t stream) {
  const float* x = (const float*)d_in[0];      // [1024, 512]
  const float* w = (const float*)d_in[1];      // [3, 5994, 512]
  const int* label = (const int*)d_in[2];      // [1024]
  float* out = (float*)d_out;                  // [2] = {loss, prec1}
  char* ws = (char*)d_ws;

  // workspace layout (bytes)
  ushort* xb = (ushort*)ws;                                    // 1,048,576 B
  ushort* wb = (ushort*)(ws + 1048576);                        // 18,481,152 B
  float* cosine = (float*)(ws + 1048576 + 18481152);           // 24,551,424 B
  float* loss_b = (float*)(ws + 1048576 + 18481152 + 24551424);
  float* corr_b = loss_b + NB;

  norm_convert<<<NB + NA * NCP, 64, 0, stream>>>(x, w, xb, wb);
  cos_gemm_mfma<<<dim3(NCP / 128, NB / 128), 256, 0, stream>>>(xb, wb, cosine);
  row_loss<<<NB, 256, 0, stream>>>(cosine, label, loss_b, corr_b);
  finalize<<<1, 256, 0, stream>>>(loss_b, corr_b, out);
}

// Round 3
// 71.903 us; speedup vs baseline: 9.7325x; 1.5398x over previous
//
#include <hip/hip_runtime.h>
#include <math.h>

// Problem constants
#define NB 1024
#define NC 5994
#define NCP 6016   // NC padded to multiple of 128 (47*128)
#define NK 512
#define NA 3
#define NT 48      // total K-steps: NA * (NK/32)
#define SCALE_F 30.0f
#define NPT 24     // ceil(NC/256)

// Margin constants
#define COS_M_F 0.9800665778412416f
#define SIN_M_F 0.19866933079506122f
#define TH_F (-0.9800665778412416f)
#define MM_F 0.039733866159012244f
#define SUB_COS_M_F 0.9982005399352042f
#define SUB_SIN_M_F (-0.05996400647944459f)
#define SUB_TH_F (-0.9982005399352042f)
#define SUB_MM_F 0.0035978403887666754f

typedef __attribute__((ext_vector_type(8))) short short8;   // 8 bf16 (4 VGPRs)
typedef __attribute__((ext_vector_type(4))) float f32x4;    // MFMA accumulator

__device__ __forceinline__ float waveReduceSum(float v) {
#pragma unroll
  for (int off = 32; off > 0; off >>= 1) v += __shfl_down(v, off);
  return v;
}

__device__ __forceinline__ void waveArgMax(float& v, int& i) {
#pragma unroll
  for (int off = 32; off > 0; off >>= 1) {
    float ov = __shfl_down(v, off);
    int oi = __shfl_down(i, off);
    if (ov > v || (ov == v && (unsigned)oi < (unsigned)i)) { v = ov; i = oi; }
  }
}

__device__ __forceinline__ ushort f2bf(float f) {
  unsigned u = __float_as_uint(f);
  u += 0x7FFFu + ((u >> 16) & 1u);
  return (ushort)(u >> 16);
}

__device__ __forceinline__ void load_lds16(const ushort* g, ushort* l) {
  __builtin_amdgcn_global_load_lds(
      (const __attribute__((address_space(1))) unsigned int*)g,
      (__attribute__((address_space(3))) unsigned int*)l, 16, 0, 0);
}

// Fused L2-normalize + bf16 convert. 4 rows per 256-thread block (1 row/wave).
__global__ __launch_bounds__(256) void norm_convert(const float* __restrict__ x,
                                                    const float* __restrict__ w,
                                                    ushort* __restrict__ xb,
                                                    ushort* __restrict__ wb) {
  const int row = blockIdx.x * 4 + (threadIdx.x >> 6);
  const int lane = threadIdx.x & 63;
  const float* src;
  ushort* dst;
  if (row < NB) {
    src = x + (size_t)row * NK;
    dst = xb + (size_t)row * NK;
  } else {
    const int r = row - NB;           // 0 .. NA*NCP-1
    const int a = r / NCP, c = r % NCP;
    dst = wb + (size_t)r * NK;
    if (c >= NC) {                    // zero-fill padding row
      ushort4 z = {0, 0, 0, 0};
      *(ushort4*)(dst + lane * 4) = z;
      *(ushort4*)(dst + 256 + lane * 4) = z;
      return;
    }
    src = w + ((size_t)a * NC + c) * NK;
  }
  const float4 v0 = *(const float4*)(src + lane * 4);
  const float4 v1 = *(const float4*)(src + 256 + lane * 4);
  float ss = v0.x * v0.x + v0.y * v0.y + v0.z * v0.z + v0.w * v0.w +
             v1.x * v1.x + v1.y * v1.y + v1.z * v1.z + v1.w * v1.w;
  ss = waveReduceSum(ss);
  ss = __shfl(ss, 0);
  const float rn = 1.0f / fmaxf(sqrtf(ss), 1e-12f);
  ushort4 o0 = {f2bf(v0.x * rn), f2bf(v0.y * rn), f2bf(v0.z * rn), f2bf(v0.w * rn)};
  ushort4 o1 = {f2bf(v1.x * rn), f2bf(v1.y * rn), f2bf(v1.z * rn), f2bf(v1.w * rn)};
  *(ushort4*)(dst + lane * 4) = o0;
  *(ushort4*)(dst + 256 + lane * 4) = o1;
}

// cosine[b,c] = max_a dot(xn[b,:], wn[a,c,:])  via bf16 MFMA, fp32 accum.
// 128x128 tile, 4 waves (2x2), 64x64/wave. Flat 48-step K-loop over
// (center, k) with 2-phase double-buffered pipeline: prefetch t+1 into the
// alternate LDS buffer, compute t, ONE vmcnt(0)+barrier per step.
// Separate __shared__ arrays per buffer -> no alias-forced early vmcnt waits.
__global__ __launch_bounds__(256) void cos_gemm_mfma(const ushort* __restrict__ Xb,
                                                     const ushort* __restrict__ Wb,
                                                     float* __restrict__ cosine) {
  __shared__ ushort sA0[128 * 32];  // 8 KB each
  __shared__ ushort sA1[128 * 32];
  __shared__ ushort sB0[128 * 32];
  __shared__ ushort sB1[128 * 32];
  const int tid = threadIdx.x;
  const int lane = tid & 63;
  const int w = tid >> 6;
  const int wr = w >> 1, wc = w & 1;
  const int b0 = blockIdx.y * 128;
  const int c0 = blockIdx.x * 128;

  // staging geometry: wave w fills LDS slots [2w, 2w+1] of 1 KB (16 rows each)
  const int e0 = w * 2;
  const int srow = e0 * 16 + (lane >> 2);
  const int scol = (lane & 3) * 8;
  const ushort* gA = Xb + (size_t)(b0 + srow) * NK + scol;
  const ushort* gB = Wb + (size_t)(c0 + srow) * NK + scol;
  const int lds0 = e0 * 512;        // ushort index of this wave's slot pair
  const int lds1 = (e0 + 1) * 512;

  // fragment-read geometry
  const int r = lane & 15;
  const int kg = lane >> 4;
  const int offA = (wr * 64 + r) * 32 + kg * 8;  // + mi*512
  const int offB = (wc * 64 + r) * 32 + kg * 8;  // + ni*512

  f32x4 best[4][4];
  f32x4 acc[4][4];
#pragma unroll
  for (int i = 0; i < 4; ++i)
#pragma unroll
    for (int j = 0; j < 4; ++j) {
#pragma unroll
      for (int q = 0; q < 4; ++q) best[i][j][q] = -INFINITY;
      acc[i][j] = (f32x4)(0.f);
    }

  // prologue: stage t=0 into buffer 0
  load_lds16(gA, (ushort*)sA0 + lds0);
  load_lds16(gA + 16 * NK, (ushort*)sA0 + lds1);
  load_lds16(gB, (ushort*)sB0 + lds0);
  load_lds16(gB + 16 * NK, (ushort*)sB0 + lds1);
  __syncthreads();

#define GEMM_BODY(T, SAr, SBr, SAw, SBw)                                        \
  {                                                                             \
    const int t_ = (T);                                                         \
    if (t_ + 1 < NT) {                                                          \
      const int tn = t_ + 1;                                                    \
      const int k0 = (tn & 15) << 5;                                            \
      const size_t boff = (size_t)(tn >> 4) * NCP * NK;                         \
      load_lds16(gA + k0, (ushort*)SAw + lds0);                                 \
      load_lds16(gA + k0 + 16 * NK, (ushort*)SAw + lds1);                       \
      load_lds16(gB + boff + k0, (ushort*)SBw + lds0);                          \
      load_lds16(gB + boff + k0 + 16 * NK, (ushort*)SBw + lds1);                \
    }                                                                           \
    short8 af[4], bf[4];                                                        \
    _Pragma("unroll") for (int mi = 0; mi < 4; ++mi)                            \
        af[mi] = *(const short8*)&SAr[offA + mi * 512];                         \
    _Pragma("unroll") for (int ni = 0; ni < 4; ++ni)                            \
        bf[ni] = *(const short8*)&SBr[offB + ni * 512];                         \
    _Pragma("unroll") for (int mi = 0; mi < 4; ++mi)                            \
        _Pragma("unroll") for (int ni = 0; ni < 4; ++ni)                        \
            acc[mi][ni] = __builtin_amdgcn_mfma_f32_16x16x32_bf16(              \
                af[mi], bf[ni], acc[mi][ni], 0, 0, 0);                          \
    if ((t_ & 15) == 15) {                                                      \
      _Pragma("unroll") for (int i = 0; i < 4; ++i)                             \
          _Pragma("unroll") for (int j = 0; j < 4; ++j) {                       \
        _Pragma("unroll") for (int q = 0; q < 4; ++q)                           \
            best[i][j][q] = fmaxf(best[i][j][q], acc[i][j][q]);                 \
        acc[i][j] = (f32x4)(0.f);                                               \
      }                                                                         \
    }                                                                           \
    __syncthreads();                                                            \
  }

  for (int t = 0; t < NT; t += 2) {
    GEMM_BODY(t, sA0, sB0, sA1, sB1)
    GEMM_BODY(t + 1, sA1, sB1, sA0, sB0)
  }
#undef GEMM_BODY

  // C/D layout: col = lane&15, row = (lane>>4)*4 + q   [measured m89/m91]
  const int q4 = (lane >> 4) * 4;
#pragma unroll
  for (int ni = 0; ni < 4; ++ni) {
    const int col = c0 + wc * 64 + ni * 16 + r;
    if (col < NC) {
#pragma unroll
      for (int mi = 0; mi < 4; ++mi) {
        const int row0 = b0 + wr * 64 + mi * 16 + q4;
#pragma unroll
        for (int q = 0; q < 4; ++q)
          cosine[(size_t)(row0 + q) * NC + col] = best[mi][ni][q];
      }
    }
  }
}

// Per-row loss: register-resident row (24 elems/thread), one global read.
// argmax -> exp-sum -> 5 masked extraction passes via per-thread bitmap.
__global__ __launch_bounds__(256) void row_loss(const float* __restrict__ cosine,
                                                const int* __restrict__ label,
                                                float* __restrict__ loss_b,
                                                float* __restrict__ corr_b) {
  __shared__ float swv[4];
  __shared__ int swi[4];
  __shared__ float s_red[4];
  __shared__ float s_maxv;
  __shared__ float s_cosL;
  __shared__ float topv[6];
  __shared__ int topi[6];

  const int b = blockIdx.x, tid = threadIdx.x;
  const int wv = tid >> 6;
  const int lab = label[b];
  const float* row = cosine + (size_t)b * NC;

  float v[NPT];
  float bv = -INFINITY;
  int bi = -1;
#pragma unroll
  for (int j = 0; j < NPT; ++j) {
    const int i = tid + j * 256;
    v[j] = (i < NC) ? row[i] : -INFINITY;
    if (v[j] > bv) { bv = v[j]; bi = i; }
  }
  if (tid == (lab & 255)) s_cosL = v[lab >> 8];
  waveArgMax(bv, bi);
  if ((tid & 63) == 0) { swv[wv] = bv; swi[wv] = bi; }
  __syncthreads();
  if (tid == 0) {
    float mv = swv[0]; int mi = swi[0];
    for (int q = 1; q < 4; ++q)
      if (swv[q] > mv || (swv[q] == mv && (unsigned)swi[q] < (unsigned)mi)) { mv = swv[q]; mi = swi[q]; }
    s_maxv = mv; topv[0] = mv; topi[0] = mi;
  }
  __syncthreads();
  const float maxv = s_maxv;

  float ps = 0.f;
#pragma unroll
  for (int j = 0; j < NPT; ++j) ps += __expf(SCALE_F * (v[j] - maxv));
  ps = waveReduceSum(ps);
  if ((tid & 63) == 0) s_red[wv] = ps;

  unsigned excl = 0;
  {
    const int wi = topi[0];  // safe: written before last sync
    if ((wi & 255) == tid) excl |= 1u << (wi >> 8);
  }

  for (int e = 1; e < 6; ++e) {
    float lv = -INFINITY;
    int li = -1;
#pragma unroll
    for (int j = 0; j < NPT; ++j)
      if (!((excl >> j) & 1u) && v[j] > lv) { lv = v[j]; li = tid + j * 256; }
    waveArgMax(lv, li);
    if ((tid & 63) == 0) { swv[wv] = lv; swi[wv] = li; }
    __syncthreads();
    if (tid == 0) {
      float mv = swv[0]; int mi = swi[0];
      for (int q = 1; q < 4; ++q)
        if (swv[q] > mv || (swv[q] == mv && (unsigned)swi[q] < (unsigned)mi)) { mv = swv[q]; mi = swi[q]; }
      topv[e] = mv; topi[e] = mi;
    }
    __syncthreads();
    const int wi = topi[e];
    if ((wi & 255) == tid) excl |= 1u << (wi >> 8);
  }

  if (tid == 0) {
    const float S = s_red[0] + s_red[1] + s_red[2] + s_red[3];
    const float m = SCALE_F * maxv;
    const float cosL = s_cosL;
    const float sineL = sqrtf(fminf(fmaxf(1.f - cosL * cosL, 0.f), 1.f));
    const float phiL = (cosL - TH_F > 0.f) ? (cosL * COS_M_F - sineL * SIN_M_F) : (cosL - MM_F);
    float adj = __expf(SCALE_F * phiL - m) - __expf(SCALE_F * cosL - m);
    int cnt = 0;
    for (int e = 0; e < 6 && cnt < 5; ++e) {
      if (topi[e] == lab) continue;
      const float c = topv[e];
      const float sine = sqrtf(fminf(fmaxf(1.f - c * c, 0.f), 1.f));
      const float sp = (c - SUB_TH_F > 0.f) ? (c * SUB_COS_M_F - sine * SUB_SIN_M_F) : (c - SUB_MM_F);
      adj += __expf(SCALE_F * sp - m) - __expf(SCALE_F * c - m);
      ++cnt;
    }
    const float Sp = S + adj;
    loss_b[b] = (logf(Sp) + m) - SCALE_F * phiL;
    corr_b[b] = (topi[0] == lab) ? 1.f : 0.f;
  }
}

__global__ __launch_bounds__(256) void finalize(const float* __restrict__ loss_b,
                                                const float* __restrict__ corr_b,
                                                float* __restrict__ out) {
  const int tid = threadIdx.x;
  float ls = 0.f, cs = 0.f;
  for (int i = tid; i < NB; i += 256) { ls += loss_b[i]; cs += corr_b[i]; }
  ls = waveReduceSum(ls);
  cs = waveReduceSum(cs);
  __shared__ float sl[4], sc[4];
  if ((tid & 63) == 0) { sl[tid >> 6] = ls; sc[tid >> 6] = cs; }
  __syncthreads();
  if (tid == 0) {
    const float L = sl[0] + sl[1] + sl[2] + sl[3];
    const float Cr = sc[0] + sc[1] + sc[2] + sc[3];
    out[0] = L / (float)NB;
    out[1] = Cr / (float)NB * 100.f;
  }
}

extern "C" void kernel_launch(void* const* d_in, const int* in_sizes, int n_in,
                              void* d_out, int out_size, void* d_ws, size_t ws_size,
                              hipStream_t stream) {
  const float* x = (const float*)d_in[0];      // [1024, 512]
  const float* w = (const float*)d_in[1];      // [3, 5994, 512]
  const int* label = (const int*)d_in[2];      // [1024]
  float* out = (float*)d_out;                  // [2] = {loss, prec1}
  char* ws = (char*)d_ws;

  ushort* xb = (ushort*)ws;                                    // 1,048,576 B
  ushort* wb = (ushort*)(ws + 1048576);                        // 18,481,152 B
  float* cosine = (float*)(ws + 1048576 + 18481152);           // 24,551,424 B
  float* loss_b = (float*)(ws + 1048576 + 18481152 + 24551424);
  float* corr_b = loss_b + NB;

  norm_convert<<<(NB + NA * NCP) / 4, 256, 0, stream>>>(x, w, xb, wb);
  cos_gemm_mfma<<<dim3(NCP / 128, NB / 128), 256, 0, stream>>>(xb, wb, cosine);
  row_loss<<<NB, 256, 0, stream>>>(cosine, label, loss_b, corr_b);
  finalize<<<1, 256, 0, stream>>>(loss_b, corr_b, out);
}